// Round 9
// baseline (29303.088 us; speedup 1.0000x reference)
//
#include <hip/hip_runtime.h>

#define T_STEPS 24000
#define DIN 598
#define NU 100      // hidden units
#define NG 400      // 4 * NU gates
#define KHALF 52    // k-slice per thread (2 x 52 = 104 = padded K)
#define KPAD 104
#define KDUP (2 * KPAD)     // duplicated h row: {h[k],h[k]} pairs, 208 floats
#define CHUNK 240   // steps per pipeline chunk
#define NCHUNK 100
#define RING 4      // ring capacity in chunks
#define RN (RING * CHUNK)   // 960 ring rows

typedef float v2f __attribute__((ext_vector_type(2)));
typedef float v4f __attribute__((ext_vector_type(4)));

// LDS-only barrier: orders ds ops without draining global loads/stores.
#define BARRIER_LDS() asm volatile("s_waitcnt lgkmcnt(0)\n\ts_barrier" ::: "memory")

// Pin a loaded value against rematerialization.
#define PIN_V2(x) asm volatile("" : "+v"(x))

// Quad-perm DPP lane-pair add: x + x_from(lane^1).  Pure VALU (no LDS pipe),
// bit-exact replacement for x + __shfl_xor(x, 1) when both lanes are active.
__device__ __forceinline__ float dpp_add_x1(float x) {
    int y = __builtin_amdgcn_mov_dpp(__float_as_int(x), 0xB1, 0xF, 0xF, true);
    return x + __int_as_float(y);
}

// ---------------------------------------------------------------------------
// cross-WG sync helpers (device-scope; per-XCD L2s are non-coherent)
// ---------------------------------------------------------------------------
__device__ __forceinline__ void wg_wait_ge(int* flag, int target) {
    if (threadIdx.x == 0) {
        while (__hip_atomic_load(flag, __ATOMIC_RELAXED, __HIP_MEMORY_SCOPE_AGENT) < target)
            __builtin_amdgcn_s_sleep(2);
    }
    __syncthreads();
    __builtin_amdgcn_fence(__ATOMIC_ACQUIRE, "agent");
}
__device__ __forceinline__ void wg_publish(int* a, int va, int* b, int vb) {
    __syncthreads();
    if (threadIdx.x == 0) {
        if (a) __hip_atomic_store(a, va, __ATOMIC_RELEASE, __HIP_MEMORY_SCOPE_AGENT);
        if (b) __hip_atomic_store(b, vb, __ATOMIC_RELEASE, __HIP_MEMORY_SCOPE_AGENT);
    }
}

// ---------------------------------------------------------------------------
__device__ __forceinline__ float sigmoid_(float x) {
    return 1.f / (1.f + __expf(-x));
}
__device__ __forceinline__ float tanh_(float x) {
    float e = __expf(2.f * x);
    return 1.f - 2.f / (e + 1.f);
}

// ---------------------------------------------------------------------------
// GEMM with bias: C[M,N] = A[M,K] @ B[K,N] + bias[N]   (fp32, 64x64 tile)
// Writes PERMUTED columns: col n=(g*100+u) lands at u*4+g (unit-major i,f,g,o).
// ---------------------------------------------------------------------------
__global__ __launch_bounds__(256) void gemm_bias_kernel(
    const float* __restrict__ A, const float* __restrict__ B,
    const float* __restrict__ bias, float* __restrict__ C,
    int M, int N, int K)
{
    __shared__ float As[16][65];
    __shared__ float Bs[16][65];
    const int tid = threadIdx.x;
    const int tx = tid & 15;
    const int ty = tid >> 4;
    const int bm = blockIdx.y * 64;
    const int bn = blockIdx.x * 64;
    float acc[4][4] = {};

    for (int k0 = 0; k0 < K; k0 += 16) {
        #pragma unroll
        for (int p = 0; p < 4; ++p) {
            int e = tid + p * 256;
            int r = e >> 4, cc = e & 15;
            int m = bm + r, k = k0 + cc;
            float v = (m < M && k < K) ? A[(long)m * K + k] : 0.f;
            As[cc][r] = v;
        }
        #pragma unroll
        for (int p = 0; p < 4; ++p) {
            int e = tid + p * 256;
            int r = e >> 6, cc = e & 63;
            int k = k0 + r, n = bn + cc;
            float v = (k < K && n < N) ? B[(long)k * N + n] : 0.f;
            Bs[r][cc] = v;
        }
        __syncthreads();
        #pragma unroll
        for (int kk = 0; kk < 16; ++kk) {
            float a[4], b[4];
            #pragma unroll
            for (int i = 0; i < 4; ++i) a[i] = As[kk][ty * 4 + i];
            #pragma unroll
            for (int j = 0; j < 4; ++j) b[j] = Bs[kk][tx * 4 + j];
            #pragma unroll
            for (int i = 0; i < 4; ++i)
                #pragma unroll
                for (int j = 0; j < 4; ++j)
                    acc[i][j] += a[i] * b[j];
        }
        __syncthreads();
    }
    #pragma unroll
    for (int i = 0; i < 4; ++i) {
        int m = bm + ty * 4 + i;
        if (m >= M) continue;
        #pragma unroll
        for (int j = 0; j < 4; ++j) {
            int n = bn + tx * 4 + j;
            if (n < N) {
                int pn = (n % 100) * 4 + (n / 100);   // unit-major permute
                C[(long)m * N + pn] = acc[i][j] + bias[n];
            }
        }
    }
}

// ---------------------------------------------------------------------------
// Recurrent role (R20 = R15 + LDS h-duplication, NO register staging).
// R19 post-mortem: staging hbuf[26] (104 VGPRs) + 104 weight VGPRs spilled
// to scratch -> +550 stall cyc/step.  The duplication idea stands: producer
// writes {h,h} with one ds_write_b64; ds_read_b128 yields
// {h[k],h[k],h[k+1],h[k+1]} -- splat pairs pre-formed on the LDS pipe,
// eliminating the 104 v_movs that VOP3P fp32 broadcast otherwise costs.
// Loads feed FMAs directly (R14 proved interleaved loads cost only ~60 cyc
// vs staged).  Per-accumulator k-order sequential 0..51 = R15 -> bit-exact.
// Do-not-revisit list: asm op_sel (R16), k-pair repack (R17), 4-way split
// (R12/R18), register staging with dup (R19) -- all regressed.
// Layout: 256 thr / 4 waves; thread 2u+s owns unit u's 4 gates over k-half s.
// ---------------------------------------------------------------------------
__device__ void rec_role(
    const float* __restrict__ xz, int xz_ring,   // [T][400] or ring, permuted
    const float* __restrict__ U,                 // [100][400] original layout
    float* __restrict__ hout, long h_stride, int h_ring, // transposed [100][h_stride]
    int* flag_up, int* done_self, int* done_down, int* flag_self,
    float* lds)                                   // >= 2*KDUP floats
{
    float* hb0 = lds;            // 208 floats: {h[k],h[k]} pairs (pad zeros)
    float* hb1 = lds + KDUP;     // 832 B offset, 16B-aligned
    const int tid = threadIdx.x;
    const bool active = tid < 2 * NU;   // 200 workers
    const int u = tid >> 1;
    const int s = tid & 1;

    // weight pairs: uf01[i] = U[k][{0,100}+u], uf23[i] = U[k][{200,300}+u]
    v2f uf01[KHALF], uf23[KHALF];
    if (active) {
        const int k0 = KHALF * s;
        #pragma unroll
        for (int i = 0; i < KHALF; ++i) {
            int k = k0 + i;
            if (k < NU) {
                uf01[i] = (v2f){U[(long)k * NG + u],          U[(long)k * NG + NU + u]};
                uf23[i] = (v2f){U[(long)k * NG + 2 * NU + u], U[(long)k * NG + 3 * NU + u]};
            } else {
                uf01[i] = (v2f){0.f, 0.f};
                uf23[i] = (v2f){0.f, 0.f};
            }
            PIN_V2(uf01[i]); PIN_V2(uf23[i]);
        }
    }
    // zero-init both duplicated buffers (208 floats each, 256 threads cover)
    if (tid < KDUP) { hb0[tid] = 0.f; hb1[tid] = 0.f; }
    float c_state = 0.f;
    // 4-deep xw register pipeline: xwp0 used this step, xwp3 in flight (t+4)
    float2 xwp0 = make_float2(0.f, 0.f), xwp1 = xwp0, xwp2 = xwp0, xwp3 = xwp0;
    float4 hbatch = make_float4(0.f, 0.f, 0.f, 0.f);

    // incremental addressing state (no per-step %RN / 64-bit muls)
    const float* xz_lane = xz + 4 * u + 2 * s;    // per-lane column base
    float* hout_u = hout + (long)u * h_stride;    // per-lane row base
    int nxt  = 4 * NG;                            // element offset of row t+4
    int hoff = 0;                                 // store offset (t-3 wrapped)
    __syncthreads();

    auto step = [&](const float* hrd, float* hwr, int t) {
        if (active) {
            // duplicated row: this thread's half starts at 2*(KHALF*s)
            const v4f* h4 = (const v4f*)(hrd + 2 * KHALF * s);
            // rotate xw pipeline and issue the t+4 prefetch
            float2 xw_use = xwp0;
            xwp0 = xwp1; xwp1 = xwp2; xwp2 = xwp3;
            if (t + 4 < T_STEPS) {
                xwp3 = *(const float2*)(xz_lane + nxt);
            }
            nxt += NG;
            if (xz_ring && nxt == RN * NG) nxt = 0;
            // FMA chain: splat pairs come straight from ds_read_b128; the
            // scheduler interleaves the 26 loads with the FMAs (no staging
            // buffer -> no register-pressure spill).  Same per-accumulator
            // k-order as R15 -> bit-exact.
            v2f a01 = (v2f){0.f, 0.f};
            v2f a23 = (v2f){0.f, 0.f};
            #pragma unroll
            for (int q = 0; q < 26; ++q) {
                v4f hv = h4[q];
                v2f plo = hv.xy;                  // {h[2q],   h[2q]}
                v2f phi = hv.zw;                  // {h[2q+1], h[2q+1]}
                a01 = __builtin_elementwise_fma(uf01[2 * q],     plo, a01);
                a23 = __builtin_elementwise_fma(uf23[2 * q],     plo, a23);
                a01 = __builtin_elementwise_fma(uf01[2 * q + 1], phi, a01);
                a23 = __builtin_elementwise_fma(uf23[2 * q + 1], phi, a23);
            }
            float ax = a01.x, ay = a01.y, az = a23.x, aw = a23.y;
            // fold this thread's xw pair: s=0 -> (i,f), s=1 -> (g,o)
            if (s == 0) { ax += xw_use.x; ay += xw_use.y; }
            else        { az += xw_use.x; aw += xw_use.y; }
            // combine k-halves with in-wave partner (lane^1) — DPP, no LDS
            ax = dpp_add_x1(ax);
            ay = dpp_add_x1(ay);
            az = dpp_add_x1(az);
            aw = dpp_add_x1(aw);
            float iv = sigmoid_(ax);
            float fv = sigmoid_(ay);
            float gv = tanh_(az);
            float ov = sigmoid_(aw);
            c_state = fv * c_state + iv * gv;    // replicated per pair
            float h = ov * tanh_(c_state);
            if (s == 0) {
                // duplicated write: one ds_write_b64 stores {h,h}
                *(float2*)&hwr[2 * u] = make_float2(h, h);   // pad stays 0
                // batch 4 steps of h, flush with one dwordx4 (t%4==3)
                int ph = t & 3;
                if      (ph == 0) hbatch.x = h;
                else if (ph == 1) hbatch.y = h;
                else if (ph == 2) hbatch.z = h;
                else {
                    hbatch.w = h;
                    *(float4*)(hout_u + hoff) = hbatch;
                    hoff += 4;
                    if (h_ring && hoff == RN) hoff = 0;
                }
            }
        }
        BARRIER_LDS();
    };

    for (int c = 0; c < NCHUNK; ++c) {
        if (flag_up) {
            int tgt = c + 2; if (tgt > NCHUNK) tgt = NCHUNK;
            wg_wait_ge(flag_up, tgt);
        }
        if (done_down && c >= RING) wg_wait_ge(done_down, c - RING + 1);
        if (c == 0 && active) {
            xwp0 = *(const float2*)(xz_lane);
            xwp1 = *(const float2*)(xz_lane + NG);
            xwp2 = *(const float2*)(xz_lane + 2 * NG);
            xwp3 = *(const float2*)(xz_lane + 3 * NG);
        }
        const int t0 = c * CHUNK;
        for (int tt = 0; tt < CHUNK; tt += 2) {
            step(hb0, hb1, t0 + tt);
            step(hb1, hb0, t0 + tt + 1);
        }
        wg_publish(done_self, c + 1, flag_self, c + 1);   // vmcnt(0) drained inside
    }
}

// ---------------------------------------------------------------------------
// Projection role — VERBATIM R15 (proj is ~4x faster than rec and off the
// critical path; keep the proven codegen).  Reads TRANSPOSED h ring
// hin[u][RN]; staging loop iterates t-major so global reads stay coalesced.
// ---------------------------------------------------------------------------
__device__ void proj_role(
    const float* __restrict__ hin,     // transposed ring [100][RN]
    const float* __restrict__ W,       // [100][400] original layout
    const float* __restrict__ bias,    // [400] gate-major index
    const float* __restrict__ g, const float* __restrict__ be,
    const float* __restrict__ m, const float* __restrict__ v,
    float* __restrict__ xzout,         // ring [RN][400] permuted
    int* flag_up, int* done_self, int* done_down, int* flag_self,
    float* lds)                         // CHUNK*KPAD floats (99.8 KB)
{
    const int tid = threadIdx.x;
    const bool active = tid < 2 * NU;
    const int u = tid >> 1;
    const int s = tid & 1;

    v2f wf01[KHALF], wf23[KHALF];
    float bx = 0.f, by = 0.f;
    if (active) {
        const int k0 = KHALF * s;
        float pbx = 0.f, pby = 0.f, pbz = 0.f, pbw = 0.f;
        #pragma unroll
        for (int i = 0; i < KHALF; ++i) {
            int k = k0 + i;
            if (k < NU) {
                float sc = g[k] * rsqrtf(v[k] + 1e-3f);
                float sh = be[k] - m[k] * sc;
                float w0 = W[(long)k * NG + u];
                float w1 = W[(long)k * NG + NU + u];
                float w2 = W[(long)k * NG + 2 * NU + u];
                float w3 = W[(long)k * NG + 3 * NU + u];
                wf01[i] = (v2f){sc * w0, sc * w1};
                wf23[i] = (v2f){sc * w2, sc * w3};
                pbx += sh * w0; pby += sh * w1; pbz += sh * w2; pbw += sh * w3;
            } else {
                wf01[i] = (v2f){0.f, 0.f};
                wf23[i] = (v2f){0.f, 0.f};
            }
            PIN_V2(wf01[i]); PIN_V2(wf23[i]);
        }
        pbx += __shfl_xor(pbx, 1); pby += __shfl_xor(pby, 1);
        pbz += __shfl_xor(pbz, 1); pbw += __shfl_xor(pbw, 1);
        if (s == 0) { bx = bias[u]          + pbx; by = bias[NU + u]     + pby; }
        else        { bx = bias[2 * NU + u] + pbz; by = bias[3 * NU + u] + pbw; }
    }

    for (int c = 0; c < NCHUNK; ++c) {
        wg_wait_ge(flag_up, c + 1);
        if (c >= RING) wg_wait_ge(done_down, c - RING + 1);
        // stage h chunk into LDS[r][k] (row stride KPAD, zeros in pad).
        // t-major iteration: consecutive tid -> consecutive t (coalesced).
        {
            const int tbase = (c % RING) * CHUNK;   // == t0 % RN
            for (int idx = tid; idx < KPAD * CHUNK; idx += 256) {
                int k = idx / CHUNK, r = idx - k * CHUNK;
                lds[r * KPAD + k] = (k < NU) ? hin[(long)k * RN + tbase + r] : 0.f;
            }
        }
        wg_publish(done_self, c + 1, (int*)0, 0);
        if (active) {
            float* ob = xzout + (size_t)(c % RING) * CHUNK * NG;
            for (int r = 0; r < CHUNK; ++r) {
                const float4* h4 = (const float4*)(lds + r * KPAD + KHALF * s);
                float4 hbuf[13];
                #pragma unroll
                for (int q = 0; q < 13; ++q) hbuf[q] = h4[q];
                v2f a01 = (v2f){0.f, 0.f};
                v2f a23 = (v2f){0.f, 0.f};
                #pragma unroll
                for (int q = 0; q < 13; ++q) {
                    float hh[4] = {hbuf[q].x, hbuf[q].y, hbuf[q].z, hbuf[q].w};
                    #pragma unroll
                    for (int j = 0; j < 4; ++j) {
                        v2f hs = (v2f){hh[j], hh[j]};
                        a01 = __builtin_elementwise_fma(wf01[4 * q + j], hs, a01);
                        a23 = __builtin_elementwise_fma(wf23[4 * q + j], hs, a23);
                    }
                }
                float ax = a01.x, ay = a01.y, az = a23.x, aw = a23.y;
                ax = dpp_add_x1(ax);
                ay = dpp_add_x1(ay);
                az = dpp_add_x1(az);
                aw = dpp_add_x1(aw);
                float2 o2 = (s == 0) ? make_float2(ax + bx, ay + by)
                                     : make_float2(az + bx, aw + by);
                *(float2*)&ob[(long)r * NG + 4 * u + 2 * s] = o2;
            }
        }
        wg_publish(flag_self, c + 1, (int*)0, 0);
    }
}

// ---------------------------------------------------------------------------
// Persistent pipeline: block 0..4 = rec1, proj2, rec2, proj3, rec3.
// waves_per_eu(1,1): one 4-wave block per CU -> full per-wave register
// budget (unified VGPR/AGPR) for the weight-resident layout.
// ---------------------------------------------------------------------------
__global__ __launch_bounds__(256)
__attribute__((amdgpu_waves_per_eu(1, 1)))
void lstm_pipe_kernel(
    const float* xw1, const float* U1,
    const float* U2, const float* W2, const float* b2,
    const float* U3, const float* W3, const float* b3,
    const float* g1, const float* be1, const float* m1, const float* v1,
    const float* g2, const float* be2, const float* m2, const float* v2,
    float* h1r, float* h2r, float* xz2r, float* xz3r, float* h3,
    int* f)
{
    extern __shared__ float smem[];
    int* f_h1  = f +   0;
    int* d_p2  = f +  32;
    int* f_xz2 = f +  64;
    int* d_r2  = f +  96;
    int* f_h2  = f + 128;
    int* d_p3  = f + 160;
    int* f_xz3 = f + 192;
    int* d_r3  = f + 224;

    switch (blockIdx.x) {
    case 0: rec_role(xw1, 0, U1, h1r, RN, 1, (int*)0, (int*)0, d_p2, f_h1, smem); break;
    case 1: proj_role(h1r, W2, b2, g1, be1, m1, v1, xz2r, f_h1, d_p2, d_r2, f_xz2, smem); break;
    case 2: rec_role(xz2r, 1, U2, h2r, RN, 1, f_xz2, d_r2, d_p3, f_h2, smem); break;
    case 3: proj_role(h2r, W3, b3, g2, be2, m2, v2, xz3r, f_h2, d_p3, d_r3, f_xz3, smem); break;
    case 4: rec_role(xz3r, 1, U3, h3, T_STEPS, 0, f_xz3, d_r3, (int*)0, (int*)0, smem); break;
    }
}

// ---------------------------------------------------------------------------
// Dense (100->3) + softmax, BN3 folded.  H is TRANSPOSED [100][T] -> the
// per-k read h[k*T+row] is perfectly coalesced across threads (rows).
// ---------------------------------------------------------------------------
__global__ __launch_bounds__(256) void dense_softmax_kernel(
    const float* __restrict__ H,    // [100][T] raw h3 (transposed)
    const float* __restrict__ Wd,
    const float* __restrict__ bd,
    const float* __restrict__ g3, const float* __restrict__ be3,
    const float* __restrict__ m3, const float* __restrict__ v3,
    float* __restrict__ out, int T)
{
    __shared__ float w[300];
    __shared__ float b[3];
    const int tid = threadIdx.x;
    for (int i = tid; i < 300; i += 256) {
        int k = i / 3;
        float sc = g3[k] * rsqrtf(v3[k] + 1e-3f);
        w[i] = Wd[i] * sc;
    }
    if (tid < 3) {
        float acc = bd[tid];
        for (int k = 0; k < NU; ++k) {
            float sc = g3[k] * rsqrtf(v3[k] + 1e-3f);
            float sh = be3[k] - m3[k] * sc;
            acc += sh * Wd[3 * k + tid];
        }
        b[tid] = acc;
    }
    __syncthreads();

    int row = blockIdx.x * blockDim.x + tid;
    if (row >= T) return;
    float s0 = b[0], s1 = b[1], s2 = b[2];
    #pragma unroll 4
    for (int k = 0; k < NU; ++k) {
        float hv = H[(long)k * T + row];
        s0 += hv * w[3 * k + 0];
        s1 += hv * w[3 * k + 1];
        s2 += hv * w[3 * k + 2];
    }
    float mx = fmaxf(s0, fmaxf(s1, s2));
    float e0 = __expf(s0 - mx), e1 = __expf(s1 - mx), e2 = __expf(s2 - mx);
    float inv = 1.f / (e0 + e1 + e2);
    out[(long)row * 3 + 0] = e0 * inv;
    out[(long)row * 3 + 1] = e1 * inv;
    out[(long)row * 3 + 2] = e2 * inv;
}

// ---------------------------------------------------------------------------
extern "C" void kernel_launch(void* const* d_in, const int* in_sizes, int n_in,
                              void* d_out, int out_size, void* d_ws, size_t ws_size,
                              hipStream_t stream)
{
    const float* x   = (const float*)d_in[0];
    const float* W1  = (const float*)d_in[1];
    const float* U1  = (const float*)d_in[2];
    const float* b1  = (const float*)d_in[3];
    const float* ga1 = (const float*)d_in[4];
    const float* be1 = (const float*)d_in[5];
    const float* mu1 = (const float*)d_in[6];
    const float* va1 = (const float*)d_in[7];
    const float* W2  = (const float*)d_in[8];
    const float* U2  = (const float*)d_in[9];
    const float* b2  = (const float*)d_in[10];
    const float* ga2 = (const float*)d_in[11];
    const float* be2 = (const float*)d_in[12];
    const float* mu2 = (const float*)d_in[13];
    const float* va2 = (const float*)d_in[14];
    const float* W3  = (const float*)d_in[15];
    const float* U3  = (const float*)d_in[16];
    const float* b3  = (const float*)d_in[17];
    const float* ga3 = (const float*)d_in[18];
    const float* be3 = (const float*)d_in[19];
    const float* mu3 = (const float*)d_in[20];
    const float* va3 = (const float*)d_in[21];
    const float* Wd  = (const float*)d_in[22];
    const float* bd  = (const float*)d_in[23];

    // workspace layout (floats) — total ~51.9 MB
    float* xw1  = (float*)d_ws;                       // T*400 (permuted)
    float* h3   = xw1  + (size_t)T_STEPS * NG;        // [100][T] transposed
    float* h1r  = h3   + (size_t)T_STEPS * NU;        // [100][RN] transposed ring
    float* h2r  = h1r  + (size_t)RN * NU;
    float* xz2r = h2r  + (size_t)RN * NU;             // RN*400 (permuted)
    float* xz3r = xz2r + (size_t)RN * NG;
    int*   flags = (int*)(xz3r + (size_t)RN * NG);    // 512 ints
    float* out = (float*)d_out;

    dim3 blk(256);
    dim3 grd((NG + 63) / 64, (T_STEPS + 63) / 64);

    // 1) input projection of layer 1 (permuted-column output)
    gemm_bias_kernel<<<grd, blk, 0, stream>>>(x, W1, b1, xw1, T_STEPS, NG, DIN);
    // 2) zero the pipeline flags
    hipMemsetAsync(flags, 0, 512 * sizeof(int), stream);
    // 3) persistent pipeline: 5 blocks x 256 threads, 99.8 KB dynamic LDS
    lstm_pipe_kernel<<<5, 256, CHUNK * KPAD * sizeof(float), stream>>>(
        xw1, U1, U2, W2, b2, U3, W3, b3,
        ga1, be1, mu1, va1, ga2, be2, mu2, va2,
        h1r, h2r, xz2r, xz3r, h3, flags);
    // 4) dense + softmax (BN3 folded, transposed-H reads)
    dense_softmax_kernel<<<(T_STEPS + 255) / 256, 256, 0, stream>>>(
        h3, Wd, bd, ga3, be3, mu3, va3, out, T_STEPS);
}

// Round 10
// 17240.936 us; speedup vs baseline: 1.6996x; 1.6996x over previous
//
#include <hip/hip_runtime.h>

#define T_STEPS 24000
#define DIN 598
#define NU 100      // hidden units
#define NG 400      // 4 * NU gates
#define KHALF 52    // k-slice per thread (2 x 52 = 104 = padded K)
#define KPAD 104
#define CHUNK 240   // steps per pipeline chunk
#define NCHUNK 100
#define RING 4      // ring capacity in chunks
#define RN (RING * CHUNK)   // 960 ring rows

typedef float v2f __attribute__((ext_vector_type(2)));

// LDS-only barrier: orders ds ops without draining global loads/stores.
#define BARRIER_LDS() asm volatile("s_waitcnt lgkmcnt(0)\n\ts_barrier" ::: "memory")

// Pin a loaded value against rematerialization.
#define PIN_V2(x) asm volatile("" : "+v"(x))

// Quad-perm DPP lane-pair add: x + x_from(lane^1).  Pure VALU (no LDS pipe),
// bit-exact replacement for x + __shfl_xor(x, 1) when both lanes are active.
__device__ __forceinline__ float dpp_add_x1(float x) {
    int y = __builtin_amdgcn_mov_dpp(__float_as_int(x), 0xB1, 0xF, 0xF, true);
    return x + __int_as_float(y);
}

// ---------------------------------------------------------------------------
// cross-WG sync helpers (device-scope; per-XCD L2s are non-coherent)
// ---------------------------------------------------------------------------
__device__ __forceinline__ void wg_wait_ge(int* flag, int target) {
    if (threadIdx.x == 0) {
        while (__hip_atomic_load(flag, __ATOMIC_RELAXED, __HIP_MEMORY_SCOPE_AGENT) < target)
            __builtin_amdgcn_s_sleep(2);
    }
    __syncthreads();
    __builtin_amdgcn_fence(__ATOMIC_ACQUIRE, "agent");
}
__device__ __forceinline__ void wg_publish(int* a, int va, int* b, int vb) {
    __syncthreads();
    if (threadIdx.x == 0) {
        if (a) __hip_atomic_store(a, va, __ATOMIC_RELEASE, __HIP_MEMORY_SCOPE_AGENT);
        if (b) __hip_atomic_store(b, vb, __ATOMIC_RELEASE, __HIP_MEMORY_SCOPE_AGENT);
    }
}

// ---------------------------------------------------------------------------
__device__ __forceinline__ float sigmoid_(float x) {
    return 1.f / (1.f + __expf(-x));
}
__device__ __forceinline__ float tanh_(float x) {
    float e = __expf(2.f * x);
    return 1.f - 2.f / (e + 1.f);
}

// ---------------------------------------------------------------------------
// GEMM with bias: C[M,N] = A[M,K] @ B[K,N] + bias[N]   (fp32, 64x64 tile)
// Writes PERMUTED columns: col n=(g*100+u) lands at u*4+g (unit-major i,f,g,o).
// ---------------------------------------------------------------------------
__global__ __launch_bounds__(256) void gemm_bias_kernel(
    const float* __restrict__ A, const float* __restrict__ B,
    const float* __restrict__ bias, float* __restrict__ C,
    int M, int N, int K)
{
    __shared__ float As[16][65];
    __shared__ float Bs[16][65];
    const int tid = threadIdx.x;
    const int tx = tid & 15;
    const int ty = tid >> 4;
    const int bm = blockIdx.y * 64;
    const int bn = blockIdx.x * 64;
    float acc[4][4] = {};

    for (int k0 = 0; k0 < K; k0 += 16) {
        #pragma unroll
        for (int p = 0; p < 4; ++p) {
            int e = tid + p * 256;
            int r = e >> 4, cc = e & 15;
            int m = bm + r, k = k0 + cc;
            float v = (m < M && k < K) ? A[(long)m * K + k] : 0.f;
            As[cc][r] = v;
        }
        #pragma unroll
        for (int p = 0; p < 4; ++p) {
            int e = tid + p * 256;
            int r = e >> 6, cc = e & 63;
            int k = k0 + r, n = bn + cc;
            float v = (k < K && n < N) ? B[(long)k * N + n] : 0.f;
            Bs[r][cc] = v;
        }
        __syncthreads();
        #pragma unroll
        for (int kk = 0; kk < 16; ++kk) {
            float a[4], b[4];
            #pragma unroll
            for (int i = 0; i < 4; ++i) a[i] = As[kk][ty * 4 + i];
            #pragma unroll
            for (int j = 0; j < 4; ++j) b[j] = Bs[kk][tx * 4 + j];
            #pragma unroll
            for (int i = 0; i < 4; ++i)
                #pragma unroll
                for (int j = 0; j < 4; ++j)
                    acc[i][j] += a[i] * b[j];
        }
        __syncthreads();
    }
    #pragma unroll
    for (int i = 0; i < 4; ++i) {
        int m = bm + ty * 4 + i;
        if (m >= M) continue;
        #pragma unroll
        for (int j = 0; j < 4; ++j) {
            int n = bn + tx * 4 + j;
            if (n < N) {
                int pn = (n % 100) * 4 + (n / 100);   // unit-major permute
                C[(long)m * N + pn] = acc[i][j] + bias[n];
            }
        }
    }
}

// ---------------------------------------------------------------------------
// Recurrent role (R21 = R15 verbatim, the verified champion @16.73 ms).
// Structure: 256 thr / 4 waves; thread 2u+s owns unit u's 4 gates over
// k-half s.  Per step: stage 13 ds_read_b128 into regs (one LDS-latency
// exposure), pk_fma gate math (bit-exact), DPP xor-1 reduce (no LDS pipe),
// 4-deep xw global prefetch, batched h stores, LDS-only barrier.
// Do-not-revisit (all regressed): asm op_sel broadcast (R16, alloc fails),
// k-pair repack (R17), 4-way worker split (R12/R18, VGPR budget conflict),
// LDS h-duplication staged (R19, scratch spill) or unstaged (R20, exposed
// LDS latency x26).  Remaining slack is the splat-mov issue tax + the
// write->barrier->read + FMA-dep-chain stall floor -- unreachable at HIP
// source level on this compiler (5 orthogonal attempts bounced).
// ---------------------------------------------------------------------------
__device__ void rec_role(
    const float* __restrict__ xz, int xz_ring,   // [T][400] or ring, permuted
    const float* __restrict__ U,                 // [100][400] original layout
    float* __restrict__ hout, long h_stride, int h_ring, // transposed [100][h_stride]
    int* flag_up, int* done_self, int* done_down, int* flag_self,
    float* lds)                                   // >= 2*KPAD floats
{
    float* hb0 = lds;            // 104 floats (pad zeros)
    float* hb1 = lds + KPAD;     // 416 B offset, 16B-aligned
    const int tid = threadIdx.x;
    const bool active = tid < 2 * NU;   // 200 workers
    const int u = tid >> 1;
    const int s = tid & 1;

    // weight pairs: uf01[i] = U[k][{0,100}+u], uf23[i] = U[k][{200,300}+u]
    v2f uf01[KHALF], uf23[KHALF];
    if (active) {
        const int k0 = KHALF * s;
        #pragma unroll
        for (int i = 0; i < KHALF; ++i) {
            int k = k0 + i;
            if (k < NU) {
                uf01[i] = (v2f){U[(long)k * NG + u],          U[(long)k * NG + NU + u]};
                uf23[i] = (v2f){U[(long)k * NG + 2 * NU + u], U[(long)k * NG + 3 * NU + u]};
            } else {
                uf01[i] = (v2f){0.f, 0.f};
                uf23[i] = (v2f){0.f, 0.f};
            }
            PIN_V2(uf01[i]); PIN_V2(uf23[i]);
        }
    }
    if (tid < KPAD) { hb0[tid] = 0.f; hb1[tid] = 0.f; }
    float c_state = 0.f;
    // 4-deep xw register pipeline: xwp0 used this step, xwp3 in flight (t+4)
    float2 xwp0 = make_float2(0.f, 0.f), xwp1 = xwp0, xwp2 = xwp0, xwp3 = xwp0;
    float4 hbatch = make_float4(0.f, 0.f, 0.f, 0.f);

    // incremental addressing state (no per-step %RN / 64-bit muls)
    const float* xz_lane = xz + 4 * u + 2 * s;    // per-lane column base
    float* hout_u = hout + (long)u * h_stride;    // per-lane row base
    int nxt  = 4 * NG;                            // element offset of row t+4
    int hoff = 0;                                 // store offset (t-3 wrapped)
    __syncthreads();

    auto step = [&](const float* hrd, float* hwr, int t) {
        if (active) {
            const float4* h4 = (const float4*)(hrd + KHALF * s);
            // phase 1: issue ALL 13 ds_read_b128 before any compute
            float4 hbuf[13];
            #pragma unroll
            for (int q = 0; q < 13; ++q) hbuf[q] = h4[q];
            __builtin_amdgcn_sched_barrier(0);
            // rotate xw pipeline and issue the t+4 prefetch (latency hides
            // under this step's FMA chain and the next 3 steps)
            float2 xw_use = xwp0;
            xwp0 = xwp1; xwp1 = xwp2; xwp2 = xwp3;
            if (t + 4 < T_STEPS) {
                xwp3 = *(const float2*)(xz_lane + nxt);
            }
            nxt += NG;
            if (xz_ring && nxt == RN * NG) nxt = 0;
            __builtin_amdgcn_sched_barrier(0);
            // phase 2: FMA chain on register-resident h
            v2f a01 = (v2f){0.f, 0.f};
            v2f a23 = (v2f){0.f, 0.f};
            #pragma unroll
            for (int q = 0; q < 13; ++q) {
                float hh[4] = {hbuf[q].x, hbuf[q].y, hbuf[q].z, hbuf[q].w};
                #pragma unroll
                for (int j = 0; j < 4; ++j) {
                    v2f hs = (v2f){hh[j], hh[j]};
                    a01 = __builtin_elementwise_fma(uf01[4 * q + j], hs, a01);
                    a23 = __builtin_elementwise_fma(uf23[4 * q + j], hs, a23);
                }
            }
            float ax = a01.x, ay = a01.y, az = a23.x, aw = a23.y;
            // fold this thread's xw pair: s=0 -> (i,f), s=1 -> (g,o)
            if (s == 0) { ax += xw_use.x; ay += xw_use.y; }
            else        { az += xw_use.x; aw += xw_use.y; }
            // combine k-halves with in-wave partner (lane^1) — DPP, no LDS
            ax = dpp_add_x1(ax);
            ay = dpp_add_x1(ay);
            az = dpp_add_x1(az);
            aw = dpp_add_x1(aw);
            float iv = sigmoid_(ax);
            float fv = sigmoid_(ay);
            float gv = tanh_(az);
            float ov = sigmoid_(aw);
            c_state = fv * c_state + iv * gv;    // replicated per pair
            float h = ov * tanh_(c_state);
            if (s == 0) {
                hwr[u] = h;                       // pad [100..103] stays 0
                // batch 4 steps of h, flush with one dwordx4 (t%4==3)
                int ph = t & 3;
                if      (ph == 0) hbatch.x = h;
                else if (ph == 1) hbatch.y = h;
                else if (ph == 2) hbatch.z = h;
                else {
                    hbatch.w = h;
                    *(float4*)(hout_u + hoff) = hbatch;
                    hoff += 4;
                    if (h_ring && hoff == RN) hoff = 0;
                }
            }
        }
        BARRIER_LDS();
    };

    for (int c = 0; c < NCHUNK; ++c) {
        if (flag_up) {
            int tgt = c + 2; if (tgt > NCHUNK) tgt = NCHUNK;
            wg_wait_ge(flag_up, tgt);
        }
        if (done_down && c >= RING) wg_wait_ge(done_down, c - RING + 1);
        if (c == 0 && active) {
            xwp0 = *(const float2*)(xz_lane);
            xwp1 = *(const float2*)(xz_lane + NG);
            xwp2 = *(const float2*)(xz_lane + 2 * NG);
            xwp3 = *(const float2*)(xz_lane + 3 * NG);
        }
        const int t0 = c * CHUNK;
        for (int tt = 0; tt < CHUNK; tt += 2) {
            step(hb0, hb1, t0 + tt);
            step(hb1, hb0, t0 + tt + 1);
        }
        wg_publish(done_self, c + 1, flag_self, c + 1);   // vmcnt(0) drained inside
    }
}

// ---------------------------------------------------------------------------
// Projection role (R15 verbatim: register-staged h reads; pk_fma + DPP).
// Reads TRANSPOSED h ring hin[u][RN]; staging loop iterates t-major so
// global reads stay coalesced.
// ---------------------------------------------------------------------------
__device__ void proj_role(
    const float* __restrict__ hin,     // transposed ring [100][RN]
    const float* __restrict__ W,       // [100][400] original layout
    const float* __restrict__ bias,    // [400] gate-major index
    const float* __restrict__ g, const float* __restrict__ be,
    const float* __restrict__ m, const float* __restrict__ v,
    float* __restrict__ xzout,         // ring [RN][400] permuted
    int* flag_up, int* done_self, int* done_down, int* flag_self,
    float* lds)                         // CHUNK*KPAD floats (99.8 KB)
{
    const int tid = threadIdx.x;
    const bool active = tid < 2 * NU;
    const int u = tid >> 1;
    const int s = tid & 1;

    v2f wf01[KHALF], wf23[KHALF];
    float bx = 0.f, by = 0.f;
    if (active) {
        const int k0 = KHALF * s;
        float pbx = 0.f, pby = 0.f, pbz = 0.f, pbw = 0.f;
        #pragma unroll
        for (int i = 0; i < KHALF; ++i) {
            int k = k0 + i;
            if (k < NU) {
                float sc = g[k] * rsqrtf(v[k] + 1e-3f);
                float sh = be[k] - m[k] * sc;
                float w0 = W[(long)k * NG + u];
                float w1 = W[(long)k * NG + NU + u];
                float w2 = W[(long)k * NG + 2 * NU + u];
                float w3 = W[(long)k * NG + 3 * NU + u];
                wf01[i] = (v2f){sc * w0, sc * w1};
                wf23[i] = (v2f){sc * w2, sc * w3};
                pbx += sh * w0; pby += sh * w1; pbz += sh * w2; pbw += sh * w3;
            } else {
                wf01[i] = (v2f){0.f, 0.f};
                wf23[i] = (v2f){0.f, 0.f};
            }
            PIN_V2(wf01[i]); PIN_V2(wf23[i]);
        }
        pbx += __shfl_xor(pbx, 1); pby += __shfl_xor(pby, 1);
        pbz += __shfl_xor(pbz, 1); pbw += __shfl_xor(pbw, 1);
        if (s == 0) { bx = bias[u]          + pbx; by = bias[NU + u]     + pby; }
        else        { bx = bias[2 * NU + u] + pbz; by = bias[3 * NU + u] + pbw; }
    }

    for (int c = 0; c < NCHUNK; ++c) {
        wg_wait_ge(flag_up, c + 1);
        if (c >= RING) wg_wait_ge(done_down, c - RING + 1);
        // stage h chunk into LDS[r][k] (row stride KPAD, zeros in pad).
        // t-major iteration: consecutive tid -> consecutive t (coalesced).
        {
            const int tbase = (c % RING) * CHUNK;   // == t0 % RN
            for (int idx = tid; idx < KPAD * CHUNK; idx += 256) {
                int k = idx / CHUNK, r = idx - k * CHUNK;
                lds[r * KPAD + k] = (k < NU) ? hin[(long)k * RN + tbase + r] : 0.f;
            }
        }
        wg_publish(done_self, c + 1, (int*)0, 0);
        if (active) {
            float* ob = xzout + (size_t)(c % RING) * CHUNK * NG;
            for (int r = 0; r < CHUNK; ++r) {
                const float4* h4 = (const float4*)(lds + r * KPAD + KHALF * s);
                float4 hbuf[13];
                #pragma unroll
                for (int q = 0; q < 13; ++q) hbuf[q] = h4[q];
                v2f a01 = (v2f){0.f, 0.f};
                v2f a23 = (v2f){0.f, 0.f};
                #pragma unroll
                for (int q = 0; q < 13; ++q) {
                    float hh[4] = {hbuf[q].x, hbuf[q].y, hbuf[q].z, hbuf[q].w};
                    #pragma unroll
                    for (int j = 0; j < 4; ++j) {
                        v2f hs = (v2f){hh[j], hh[j]};
                        a01 = __builtin_elementwise_fma(wf01[4 * q + j], hs, a01);
                        a23 = __builtin_elementwise_fma(wf23[4 * q + j], hs, a23);
                    }
                }
                float ax = a01.x, ay = a01.y, az = a23.x, aw = a23.y;
                ax = dpp_add_x1(ax);
                ay = dpp_add_x1(ay);
                az = dpp_add_x1(az);
                aw = dpp_add_x1(aw);
                float2 o2 = (s == 0) ? make_float2(ax + bx, ay + by)
                                     : make_float2(az + bx, aw + by);
                *(float2*)&ob[(long)r * NG + 4 * u + 2 * s] = o2;
            }
        }
        wg_publish(flag_self, c + 1, (int*)0, 0);
    }
}

// ---------------------------------------------------------------------------
// Persistent pipeline: block 0..4 = rec1, proj2, rec2, proj3, rec3.
// waves_per_eu(1,1): one 4-wave block per CU -> full per-wave register
// budget for the weight + hbuf resident layout.
// ---------------------------------------------------------------------------
__global__ __launch_bounds__(256)
__attribute__((amdgpu_waves_per_eu(1, 1)))
void lstm_pipe_kernel(
    const float* xw1, const float* U1,
    const float* U2, const float* W2, const float* b2,
    const float* U3, const float* W3, const float* b3,
    const float* g1, const float* be1, const float* m1, const float* v1,
    const float* g2, const float* be2, const float* m2, const float* v2,
    float* h1r, float* h2r, float* xz2r, float* xz3r, float* h3,
    int* f)
{
    extern __shared__ float smem[];
    int* f_h1  = f +   0;
    int* d_p2  = f +  32;
    int* f_xz2 = f +  64;
    int* d_r2  = f +  96;
    int* f_h2  = f + 128;
    int* d_p3  = f + 160;
    int* f_xz3 = f + 192;
    int* d_r3  = f + 224;

    switch (blockIdx.x) {
    case 0: rec_role(xw1, 0, U1, h1r, RN, 1, (int*)0, (int*)0, d_p2, f_h1, smem); break;
    case 1: proj_role(h1r, W2, b2, g1, be1, m1, v1, xz2r, f_h1, d_p2, d_r2, f_xz2, smem); break;
    case 2: rec_role(xz2r, 1, U2, h2r, RN, 1, f_xz2, d_r2, d_p3, f_h2, smem); break;
    case 3: proj_role(h2r, W3, b3, g2, be2, m2, v2, xz3r, f_h2, d_p3, d_r3, f_xz3, smem); break;
    case 4: rec_role(xz3r, 1, U3, h3, T_STEPS, 0, f_xz3, d_r3, (int*)0, (int*)0, smem); break;
    }
}

// ---------------------------------------------------------------------------
// Dense (100->3) + softmax, BN3 folded.  H is TRANSPOSED [100][T] -> the
// per-k read h[k*T+row] is perfectly coalesced across threads (rows).
// ---------------------------------------------------------------------------
__global__ __launch_bounds__(256) void dense_softmax_kernel(
    const float* __restrict__ H,    // [100][T] raw h3 (transposed)
    const float* __restrict__ Wd,
    const float* __restrict__ bd,
    const float* __restrict__ g3, const float* __restrict__ be3,
    const float* __restrict__ m3, const float* __restrict__ v3,
    float* __restrict__ out, int T)
{
    __shared__ float w[300];
    __shared__ float b[3];
    const int tid = threadIdx.x;
    for (int i = tid; i < 300; i += 256) {
        int k = i / 3;
        float sc = g3[k] * rsqrtf(v3[k] + 1e-3f);
        w[i] = Wd[i] * sc;
    }
    if (tid < 3) {
        float acc = bd[tid];
        for (int k = 0; k < NU; ++k) {
            float sc = g3[k] * rsqrtf(v3[k] + 1e-3f);
            float sh = be3[k] - m3[k] * sc;
            acc += sh * Wd[3 * k + tid];
        }
        b[tid] = acc;
    }
    __syncthreads();

    int row = blockIdx.x * blockDim.x + tid;
    if (row >= T) return;
    float s0 = b[0], s1 = b[1], s2 = b[2];
    #pragma unroll 4
    for (int k = 0; k < NU; ++k) {
        float hv = H[(long)k * T + row];
        s0 += hv * w[3 * k + 0];
        s1 += hv * w[3 * k + 1];
        s2 += hv * w[3 * k + 2];
    }
    float mx = fmaxf(s0, fmaxf(s1, s2));
    float e0 = __expf(s0 - mx), e1 = __expf(s1 - mx), e2 = __expf(s2 - mx);
    float inv = 1.f / (e0 + e1 + e2);
    out[(long)row * 3 + 0] = e0 * inv;
    out[(long)row * 3 + 1] = e1 * inv;
    out[(long)row * 3 + 2] = e2 * inv;
}

// ---------------------------------------------------------------------------
extern "C" void kernel_launch(void* const* d_in, const int* in_sizes, int n_in,
                              void* d_out, int out_size, void* d_ws, size_t ws_size,
                              hipStream_t stream)
{
    const float* x   = (const float*)d_in[0];
    const float* W1  = (const float*)d_in[1];
    const float* U1  = (const float*)d_in[2];
    const float* b1  = (const float*)d_in[3];
    const float* ga1 = (const float*)d_in[4];
    const float* be1 = (const float*)d_in[5];
    const float* mu1 = (const float*)d_in[6];
    const float* va1 = (const float*)d_in[7];
    const float* W2  = (const float*)d_in[8];
    const float* U2  = (const float*)d_in[9];
    const float* b2  = (const float*)d_in[10];
    const float* ga2 = (const float*)d_in[11];
    const float* be2 = (const float*)d_in[12];
    const float* mu2 = (const float*)d_in[13];
    const float* va2 = (const float*)d_in[14];
    const float* W3  = (const float*)d_in[15];
    const float* U3  = (const float*)d_in[16];
    const float* b3  = (const float*)d_in[17];
    const float* ga3 = (const float*)d_in[18];
    const float* be3 = (const float*)d_in[19];
    const float* mu3 = (const float*)d_in[20];
    const float* va3 = (const float*)d_in[21];
    const float* Wd  = (const float*)d_in[22];
    const float* bd  = (const float*)d_in[23];

    // workspace layout (floats) — total ~51.9 MB
    float* xw1  = (float*)d_ws;                       // T*400 (permuted)
    float* h3   = xw1  + (size_t)T_STEPS * NG;        // [100][T] transposed
    float* h1r  = h3   + (size_t)T_STEPS * NU;        // [100][RN] transposed ring
    float* h2r  = h1r  + (size_t)RN * NU;
    float* xz2r = h2r  + (size_t)RN * NU;             // RN*400 (permuted)
    float* xz3r = xz2r + (size_t)RN * NG;
    int*   flags = (int*)(xz3r + (size_t)RN * NG);    // 512 ints
    float* out = (float*)d_out;

    dim3 blk(256);
    dim3 grd((NG + 63) / 64, (T_STEPS + 63) / 64);

    // 1) input projection of layer 1 (permuted-column output)
    gemm_bias_kernel<<<grd, blk, 0, stream>>>(x, W1, b1, xw1, T_STEPS, NG, DIN);
    // 2) zero the pipeline flags
    hipMemsetAsync(flags, 0, 512 * sizeof(int), stream);
    // 3) persistent pipeline: 5 blocks x 256 threads, 99.8 KB dynamic LDS
    lstm_pipe_kernel<<<5, 256, CHUNK * KPAD * sizeof(float), stream>>>(
        xw1, U1, U2, W2, b2, U3, W3, b3,
        ga1, be1, mu1, va1, ga2, be2, mu2, va2,
        h1r, h2r, xz2r, xz3r, h3, flags);
    // 4) dense + softmax (BN3 folded, transposed-H reads)
    dense_softmax_kernel<<<(T_STEPS + 255) / 256, 256, 0, stream>>>(
        h3, Wd, bd, ga3, be3, mu3, va3, out, T_STEPS);
}